// Round 10
// baseline (54.960 us; speedup 1.0000x reference)
//
#include <hip/hip_runtime.h>
#include <math.h>

// MaxofErosions2D, packed-f16, natural-pair LDS tile, FINE-GRAINED blocks.
// out[b,h,w,f] = max_c min_{dy,dx} ( x[b,h+dy-2,w+dx-2,c] - kern[4-dy,4-dx,c,f] )
// x: (32,256,256,3) f32, kern: (5,5,3,8) f32, out: (32,256,256,8) f32.
//
// R10 change vs R9: block 4rows/256thr -> 2rows/128thr (4096 blocks), XCD-
// bijective swizzle so row-adjacent tiles share an XCD L2. Rationale: idle
// time tracks grid granularity (R3 8192blk: 21% idle; 2048blk: 44%; R8
// 1024blk: 48%) -- more/smaller blocks break the stage->compute->store
// phase-lock and stream refills. Core math unchanged (busy ~30us = f16-pk
// VALU floor hypothesis being tested).

typedef _Float16 h2 __attribute__((ext_vector_type(2)));

static __device__ __forceinline__ h2 cvt_pk(float a, float b) {
    return __builtin_bit_cast(h2, __builtin_amdgcn_cvt_pkrtz(a, b));
}
static __device__ __forceinline__ h2 u2h(unsigned u) {
    return __builtin_bit_cast(h2, u);
}

#define Hq 256
#define RSTR 396                  // h2 per tile row (264 cols * 3 f16 / 2)
#define TROWS 6                   // 2 output rows + 4 halo
#define TILE_H2 (TROWS * RSTR)    // 2376 h2 = 9504 B
#define INF2 0x7C007C00u          // +inf f16 pair

__global__ __launch_bounds__(128) void maxero_fg(
    const float* __restrict__ x,
    const float* __restrict__ kern,
    float* __restrict__ out)
{
    __shared__ __align__(16) h2 xlds[TILE_H2];
    __shared__ __align__(16) h2 klds[25 * 12];

    const int tid  = threadIdx.x;
    // XCD-bijective swizzle: HW round-robins blockIdx over 8 XCDs; remap so
    // each XCD gets 512 CONSECUTIVE logical tiles (row-adjacent -> L2 reuse).
    const int orig = blockIdx.x;                 // 4096 blocks
    const int L    = (orig & 7) * 512 + (orig >> 3);
    const int b    = L >> 7;                     // image 0..31
    const int h0   = (L & 127) << 1;             // first output row (2 rows/block)

    // ---- stage kernel: pre-flipped, filter-pair packed (300 > 128: strided!)
    for (int i = tid; i < 300; i += 128) {
        int tap = i / 12;
        int rem = i - tap * 12;
        int c = rem >> 2, fp = rem & 3;
        int dy = tap / 5, dx = tap - dy * 5;
        const float* kp = kern + (((4 - dy) * 5 + (4 - dx)) * 24) + c * 8 + fp * 2;
        klds[i] = cvt_pk(kp[0], kp[1]);
    }

    // ---- stage x tile: 6 rows x 256 cols x 3 ch = 1152 float4 chunks (9/thread)
    const float* xb = x + (size_t)b * (Hq * 256 * 3);
    #pragma unroll
    for (int k = 0; k < 9; ++k) {
        int chunk = tid + k * 128;            // 0..1151
        int rr    = chunk / 192;              // 192 float4 per row
        int off   = (chunk - rr * 192) * 4;   // float offset in row
        int r     = h0 - 2 + rr;
        bool rv   = (unsigned)r < (unsigned)Hq;
        int rc    = min(max(r, 0), Hq - 1);
        const float4 v = *reinterpret_cast<const float4*>(xb + rc * 768 + off);
        h2* d = &xlds[rr * RSTR + 9 + (off >> 1)];
        d[0] = rv ? cvt_pk(v.x, v.y) : u2h(INF2);
        d[1] = rv ? cvt_pk(v.z, v.w) : u2h(INF2);
    }
    // halo fill: 6 rows x (9 left h2 + 3 right h2) = 72 entries
    if (tid < 72) {
        int rr = tid / 12, p = tid - rr * 12;
        xlds[rr * RSTR + (p < 9 ? p : 384 + p)] = u2h(INF2);
    }
    __syncthreads();

    const int hrow = tid >> 6;           // 0..1
    const int w0   = (tid & 63) << 2;    // 0..252

    h2 ero[4][3][4];
    #pragma unroll
    for (int p = 0; p < 4; ++p)
        #pragma unroll
        for (int c = 0; c < 3; ++c)
            #pragma unroll
            for (int fp = 0; fp < 4; ++fp)
                ero[p][c][fp] = u2h(INF2);

    #pragma unroll
    for (int dy = 0; dy < 5; ++dy) {
        // 24 f16 (cols w0-2..w0+5, 3 ch) = 12 h2, base h2 = row*396 + 6 + 3*w0/2 (even)
        const uint2* rp = reinterpret_cast<const uint2*>(
            &xlds[(hrow + dy) * RSTR + 6 + ((3 * w0) >> 1)]);
        unsigned nat[12];
        #pragma unroll
        for (int q = 0; q < 6; ++q) {
            uint2 t = rp[q];
            nat[q * 2 + 0] = t.x;
            nat[q * 2 + 1] = t.y;
        }
        #pragma unroll
        for (int dx = 0; dx < 5; ++dx) {
            const uint4* kk = reinterpret_cast<const uint4*>(&klds[(dy * 5 + dx) * 12]);
            uint4 k0 = kk[0], k1 = kk[1], k2 = kk[2];   // broadcast, conflict-free
            const unsigned kf[12] = { k0.x, k0.y, k0.z, k0.w,
                                      k1.x, k1.y, k1.z, k1.w,
                                      k2.x, k2.y, k2.z, k2.w };
            #pragma unroll
            for (int p = 0; p < 4; ++p)
                #pragma unroll
                for (int c = 0; c < 3; ++c) {
                    const int e = (p + dx) * 3 + c;      // element 0..23
                    _Float16 s = u2h(nat[e >> 1])[e & 1];
                    h2 xx = { s, s };                    // op_sel fold / v_perm (CSE'd)
                    #pragma unroll
                    for (int fp = 0; fp < 4; ++fp) {
                        h2 cand = xx - u2h(kf[c * 4 + fp]);
                        ero[p][c][fp] = __builtin_elementwise_min(ero[p][c][fp], cand);
                    }
                }
        }
    }

    // ---- epilogue: channel max, f32 output, 2x float4 per pixel
    const size_t rowbase = (size_t)b * 65536 + (size_t)(h0 + hrow) * 256 + w0;
    #pragma unroll
    for (int p = 0; p < 4; ++p) {
        float of[8];
        #pragma unroll
        for (int fp = 0; fp < 4; ++fp) {
            h2 m = __builtin_elementwise_max(
                       __builtin_elementwise_max(ero[p][0][fp], ero[p][1][fp]),
                       ero[p][2][fp]);
            of[fp * 2 + 0] = (float)m[0];
            of[fp * 2 + 1] = (float)m[1];
        }
        float* op = out + (rowbase + p) * 8;
        reinterpret_cast<float4*>(op)[0] = make_float4(of[0], of[1], of[2], of[3]);
        reinterpret_cast<float4*>(op)[1] = make_float4(of[4], of[5], of[6], of[7]);
    }
}

extern "C" void kernel_launch(void* const* d_in, const int* in_sizes, int n_in,
                              void* d_out, int out_size, void* d_ws, size_t ws_size,
                              hipStream_t stream) {
    const float* x    = (const float*)d_in[0];
    const float* kern = (const float*)d_in[1];
    float* out        = (float*)d_out;
    maxero_fg<<<4096, 128, 0, stream>>>(x, kern, out);  // 32 img x 128 row-pairs
}

// Round 11
// 51.410 us; speedup vs baseline: 1.0691x; 1.0691x over previous
//
#include <hip/hip_runtime.h>
#include <math.h>

// MaxofErosions2D, pixel-pair-packed f16, channel-planar LDS, dup-k table.
// out[b,h,w,f] = max_c min_{dy,dx} ( x[b,h+dy-2,w+dx-2,c] - kern[4-dy,4-dx,c,f] )
// x: (32,256,256,3) f32, kern: (5,5,3,8) f32, out: (32,256,256,8) f32.
//
// R11 single-variable test vs R9: eliminate ALL per-use f16 duplication.
//  - x tile stored channel-planar: h2 = two adjacent PIXELS (same channel).
//  - kernel stored pre-duplicated {k,k} in LDS (600 h2 = 2400 B).
//  - inner op: h2(x_p0,x_p1) - h2(k,k): both operands natural h2 regs ->
//    guaranteed-foldable v_pk_add/v_pk_min, no extract/splat scalarization.
//  - odd-dx pairs via v_alignbit (9/dy = 45/thread, vs R9's ~300 splats).
// Block = 4 rows x 256 w, thread = 4 px (= R9 geometry, known best).

typedef _Float16 h2 __attribute__((ext_vector_type(2)));

static __device__ __forceinline__ h2 cvt_pk(float a, float b) {
    return __builtin_bit_cast(h2, __builtin_amdgcn_cvt_pkrtz(a, b));
}
static __device__ __forceinline__ h2 u2h(unsigned u) {
    return __builtin_bit_cast(h2, u);
}

#define Hq 256
#define RST 132             // h2 per plane row (264 f16: cols -2..261, idx = col+2)
#define PST (8 * RST)       // 1056 h2 per channel plane (8 tile rows)
#define TILE_H2 (3 * PST)   // 3168 h2 = 12672 B
#define INF2 0x7C007C00u    // +inf f16 pair

__global__ __launch_bounds__(256) void maxero_pp(
    const float* __restrict__ x,
    const float* __restrict__ kern,
    float* __restrict__ out)
{
    __shared__ __align__(16) h2 xp[TILE_H2];
    __shared__ __align__(16) h2 kd[600];   // [tap][c][f] = {k,k} dup pairs

    const int tid = threadIdx.x;
    const int bI  = blockIdx.x;        // 2048 blocks
    const int b   = bI >> 6;           // image
    const int h0  = (bI & 63) << 2;    // first output row

    // ---- stage dup'd kernel: pre-flipped (600 > 256: strided!)
    for (int i = tid; i < 600; i += 256) {
        int tap = i / 24, rem = i - tap * 24;
        int c = rem >> 3, f = rem & 7;
        int dy = tap / 5, dx = tap - dy * 5;
        float v = kern[((4 - dy) * 5 + (4 - dx)) * 24 + c * 8 + f];
        kd[i] = cvt_pk(v, v);
    }

    // ---- stage x planar: 512 groups of 3 float4 (= 4 pixels x 3ch), 2/thread
    const float* xb = x + (size_t)b * (Hq * 256 * 3);
    #pragma unroll
    for (int k = 0; k < 2; ++k) {
        int g   = tid + k * 256;          // 0..511
        int rr  = g >> 6;                 // tile row 0..7
        int pg  = g & 63;                 // pixel group: cols 4pg..4pg+3
        int r   = h0 - 2 + rr;
        bool rv = (unsigned)r < (unsigned)Hq;
        int rc  = min(max(r, 0), Hq - 1);
        const float4* gp = reinterpret_cast<const float4*>(xb + rc * 768 + pg * 12);
        float4 v0 = gp[0], v1 = gp[1], v2 = gp[2];
        const float fv[12] = { v0.x, v0.y, v0.z, v0.w,
                               v1.x, v1.y, v1.z, v1.w,
                               v2.x, v2.y, v2.z, v2.w };
        int base = rr * RST + 2 * pg + 1;          // h2 idx of (cols 4pg,4pg+1)
        #pragma unroll
        for (int c = 0; c < 3; ++c) {
            xp[c * PST + base + 0] = rv ? cvt_pk(fv[c],     fv[3 + c]) : u2h(INF2);
            xp[c * PST + base + 1] = rv ? cvt_pk(fv[6 + c], fv[9 + c]) : u2h(INF2);
        }
    }
    // halo: per (c,row): h2 idx 0 (cols -2,-1) and 129 (cols 256,257)
    if (tid < 48) {
        int c = tid >> 4, rem = tid & 15;
        int rr = rem >> 1, side = rem & 1;
        xp[c * PST + rr * RST + (side ? 129 : 0)] = u2h(INF2);
    }
    __syncthreads();

    const int hrow = tid >> 6;           // 0..3
    const int w0   = (tid & 63) << 2;    // 0..252

    h2 e01[3][8], e23[3][8];             // pixel-pairs (w0,w0+1) and (w0+2,w0+3)
    #pragma unroll
    for (int c = 0; c < 3; ++c)
        #pragma unroll
        for (int f = 0; f < 8; ++f) {
            e01[c][f] = u2h(INF2);
            e23[c][f] = u2h(INF2);
        }

    #pragma unroll
    for (int dy = 0; dy < 5; ++dy) {
        // per channel: 4 aligned pairs (cols w0-2..w0+5) + 3 shifted pairs
        unsigned a[3][4], mis[3][3];
        #pragma unroll
        for (int c = 0; c < 3; ++c) {
            const h2* xr = &xp[c * PST + (hrow + dy) * RST + (w0 >> 1)];
            uint2 u0 = *reinterpret_cast<const uint2*>(xr);      // 8B-aligned
            uint2 u1 = *reinterpret_cast<const uint2*>(xr + 2);
            a[c][0] = u0.x; a[c][1] = u0.y; a[c][2] = u1.x; a[c][3] = u1.y;
            mis[c][0] = __builtin_amdgcn_alignbit(a[c][1], a[c][0], 16);
            mis[c][1] = __builtin_amdgcn_alignbit(a[c][2], a[c][1], 16);
            mis[c][2] = __builtin_amdgcn_alignbit(a[c][3], a[c][2], 16);
        }
        #pragma unroll
        for (int dx = 0; dx < 5; ++dx) {
            #pragma unroll
            for (int c = 0; c < 3; ++c) {
                // pixel pairs for this tap: cols (w0+dx-2, w0+dx-1), (w0+dx, w0+dx+1)
                h2 p01 = u2h((dx & 1) ? mis[c][dx >> 1]       : a[c][dx >> 1]);
                h2 p23 = u2h((dx & 1) ? mis[c][(dx >> 1) + 1] : a[c][(dx >> 1) + 1]);
                const uint4* kk = reinterpret_cast<const uint4*>(
                    &kd[(dy * 5 + dx) * 24 + c * 8]);
                uint4 k0 = kk[0], k1 = kk[1];   // broadcast, conflict-free
                const unsigned kf[8] = { k0.x, k0.y, k0.z, k0.w,
                                         k1.x, k1.y, k1.z, k1.w };
                #pragma unroll
                for (int f = 0; f < 8; ++f) {
                    e01[c][f] = __builtin_elementwise_min(e01[c][f], p01 - u2h(kf[f]));
                    e23[c][f] = __builtin_elementwise_min(e23[c][f], p23 - u2h(kf[f]));
                }
            }
        }
    }

    // ---- epilogue: channel max, unpack pairs, f32 out, 2x float4 per pixel
    float o0[8], o1[8], o2[8], o3[8];
    #pragma unroll
    for (int f = 0; f < 8; ++f) {
        h2 m01 = __builtin_elementwise_max(
                     __builtin_elementwise_max(e01[0][f], e01[1][f]), e01[2][f]);
        h2 m23 = __builtin_elementwise_max(
                     __builtin_elementwise_max(e23[0][f], e23[1][f]), e23[2][f]);
        o0[f] = (float)m01[0]; o1[f] = (float)m01[1];
        o2[f] = (float)m23[0]; o3[f] = (float)m23[1];
    }
    const size_t rowbase = (size_t)b * 65536 + (size_t)(h0 + hrow) * 256 + w0;
    float* op = out + rowbase * 8;
    reinterpret_cast<float4*>(op)[0] = make_float4(o0[0], o0[1], o0[2], o0[3]);
    reinterpret_cast<float4*>(op)[1] = make_float4(o0[4], o0[5], o0[6], o0[7]);
    reinterpret_cast<float4*>(op)[2] = make_float4(o1[0], o1[1], o1[2], o1[3]);
    reinterpret_cast<float4*>(op)[3] = make_float4(o1[4], o1[5], o1[6], o1[7]);
    reinterpret_cast<float4*>(op)[4] = make_float4(o2[0], o2[1], o2[2], o2[3]);
    reinterpret_cast<float4*>(op)[5] = make_float4(o2[4], o2[5], o2[6], o2[7]);
    reinterpret_cast<float4*>(op)[6] = make_float4(o3[0], o3[1], o3[2], o3[3]);
    reinterpret_cast<float4*>(op)[7] = make_float4(o3[4], o3[5], o3[6], o3[7]);
}

extern "C" void kernel_launch(void* const* d_in, const int* in_sizes, int n_in,
                              void* d_out, int out_size, void* d_ws, size_t ws_size,
                              hipStream_t stream) {
    const float* x    = (const float*)d_in[0];
    const float* kern = (const float*)d_in[1];
    float* out        = (float*)d_out;
    maxero_pp<<<2048, 256, 0, stream>>>(x, kern, out);  // 32 img x 64 row-groups
}